// Round 16
// baseline (345.467 us; speedup 1.0000x reference)
//
#include <hip/hip_runtime.h>
#include <math.h>

typedef __attribute__((ext_vector_type(4))) float f32x4;
typedef __attribute__((ext_vector_type(4))) float f4;
typedef __attribute__((ext_vector_type(8))) _Float16 h8;
typedef __attribute__((ext_vector_type(4))) _Float16 h4;
typedef __attribute__((ext_vector_type(8))) unsigned short us8;

static __device__ __forceinline__ h8 ld8h(const _Float16* p) {
    return __builtin_bit_cast(h8, *(const us8*)p);
}
static __device__ __forceinline__ void glds16(const void* g, void* l) {
    __builtin_amdgcn_global_load_lds((const __attribute__((address_space(1))) unsigned int*)g,
                                     (__attribute__((address_space(3))) unsigned int*)l, 16, 0, 0);
}

// ---------------------------------------------------------------------------
// fp32 -> fp16, 8 elements/thread
// ---------------------------------------------------------------------------
__global__ void convert_half(const float* __restrict__ in, _Float16* __restrict__ out, int n8) {
    int i = blockIdx.x * blockDim.x + threadIdx.x;
    if (i >= n8) return;
    f4 v0 = *(const f4*)(in + (size_t)i * 8);
    f4 v1 = *(const f4*)(in + (size_t)i * 8 + 4);
    h8 o;
#pragma unroll
    for (int j = 0; j < 4; j++) {
        o[j] = (_Float16)v0[j];
        o[j + 4] = (_Float16)v1[j];
    }
    *(h8*)(out + (size_t)i * 8) = o;
}

// ---------------------------------------------------------------------------
// SuRoPE cos/sin table
// ---------------------------------------------------------------------------
__global__ void rope_table(const float* __restrict__ sf, float* __restrict__ cs,
                           float* __restrict__ sn, float rope_scale) {
    int i = blockIdx.x * blockDim.x + threadIdx.x;  // 2048*48
    const int j = i % 48, l = i / 48;
    const float e = (float)(2 * j) / 96.0f;
    const float inv = 1.0f / (sf[j] * powf(10000.0f, e));
    const float ang = (float)l * inv;
    cs[i] = cosf(ang) * rope_scale;
    sn[i] = sinf(ang) * rope_scale;
}

// ---------------------------------------------------------------------------
// QKV GEMM, fused SuRoPE + head-split + V-transpose epilogue. BM=128, BN=192,
// grid 48x16 = 768 blocks = exactly 3/CU. Q scaled by attn_scale*log2(e).
// ---------------------------------------------------------------------------
__global__ __launch_bounds__(256, 3) void gemm_qkv(
    const _Float16* __restrict__ A, const _Float16* __restrict__ B,
    const float* __restrict__ cs, const float* __restrict__ sn,
    _Float16* __restrict__ Qh, _Float16* __restrict__ Kh, _Float16* __restrict__ Vt,
    float q_scale) {
    const int K = 3072;
    __shared__ _Float16 As[2][128][32], Bs[2][192][32];
    const int t = threadIdx.x;
    const int lane = t & 63, w = t >> 6;
    const int bm = blockIdx.y * 128, bn = blockIdx.x * 192;
    const int wm = w >> 1, wn = w & 1;
    const int l15 = lane & 15, l4 = lane >> 4;

    int car[2], cas[2], cbr[3], cbs[3];
#pragma unroll
    for (int i = 0; i < 2; i++) {
        const int c = t + i * 256;
        car[i] = c >> 2;
        cas[i] = (((c & 3) ^ ((car[i] >> 1) & 3)) * 8);
    }
#pragma unroll
    for (int i = 0; i < 3; i++) {
        const int c = t + i * 256;
        cbr[i] = c >> 2;
        cbs[i] = (((c & 3) ^ ((cbr[i] >> 1) & 3)) * 8);
    }

    f32x4 acc[4][6] = {};

#define STG_QKV(k0_, buf)                                                              \
    {                                                                                  \
        _Float16* ab = &As[(buf)][0][0];                                               \
        _Float16* bb = &Bs[(buf)][0][0];                                               \
        _Pragma("unroll") for (int i = 0; i < 2; i++)                                  \
            glds16(A + (size_t)(bm + car[i]) * K + (k0_) + cas[i], ab + (t + i * 256) * 8); \
        _Pragma("unroll") for (int i = 0; i < 3; i++)                                  \
            glds16(B + (size_t)(bn + cbr[i]) * K + (k0_) + cbs[i], bb + (t + i * 256) * 8); \
    }

    STG_QKV(0, 0)

    int cur = 0;
    for (int k0 = 0; k0 < K; k0 += 32) {
        __syncthreads();
        if (k0 + 32 < K) STG_QKV(k0 + 32, cur ^ 1)
        h8 af[4], bf[6];
#pragma unroll
        for (int m = 0; m < 4; m++) {
            const int row = wm * 64 + m * 16 + l15;
            af[m] = ld8h(&As[cur][row][(l4 ^ ((row >> 1) & 3)) * 8]);
        }
#pragma unroll
        for (int n = 0; n < 6; n++) {
            const int row = wn * 96 + n * 16 + l15;
            bf[n] = ld8h(&Bs[cur][row][(l4 ^ ((row >> 1) & 3)) * 8]);
        }
#pragma unroll
        for (int m = 0; m < 4; m++)
#pragma unroll
            for (int n = 0; n < 6; n++)
                acc[m][n] = __builtin_amdgcn_mfma_f32_16x16x32_f16(af[m], bf[n], acc[m][n], 0, 0, 0);
        cur ^= 1;
    }
#undef STG_QKV

    const int opcol0 = bn + wn * 96;
    const int which = opcol0 / 3072;
    const int h = (opcol0 % 3072) / 96;

    if (which == 2) {
        // fused transpose: Vt[h][d][l], d = n*16+l15, l = bm+wm*64+m*16+l4*4+r
#pragma unroll
        for (int m = 0; m < 4; m++)
#pragma unroll
            for (int n = 0; n < 6; n++) {
                h4 v;
#pragma unroll
                for (int r = 0; r < 4; r++) v[r] = (_Float16)acc[m][n][r];
                *(h4*)(Vt + ((size_t)h * 96 + n * 16 + l15) * 2048 + bm + wm * 64 + m * 16 + l4 * 4) = v;
            }
    } else {
        _Float16* dst = (which == 0) ? Qh : Kh;
        const float qs = (which == 0) ? q_scale : 1.0f;
#pragma unroll
        for (int m = 0; m < 4; m++)
#pragma unroll
            for (int r = 0; r < 4; r++) {
                const int l = bm + wm * 64 + m * 16 + l4 * 4 + r;
                const float* csl = cs + l * 48;
                const float* snl = sn + l * 48;
                const size_t rowb = ((size_t)h * 2048 + l) * 96;
#pragma unroll
                for (int n = 0; n < 3; n++) {
                    const int j = n * 16 + l15;
                    const float c = csl[j], s = snl[j];
                    const float lo = acc[m][n][r], hi = acc[m][n + 3][r];
                    dst[rowb + j] = (_Float16)((lo * c - hi * s) * qs);
                    dst[rowb + j + 48] = (_Float16)((hi * c + lo * s) * qs);
                }
            }
    }
}

// ---------------------------------------------------------------------------
// Projection GEMM: BM=128, BN=96, grid 32x16 = 512 blocks = uniform 2/CU.
// ---------------------------------------------------------------------------
__global__ __launch_bounds__(256, 3) void gemm_p(
    const _Float16* __restrict__ A, const _Float16* __restrict__ B,
    float* __restrict__ C, int M, int N, int K) {
    __shared__ _Float16 As[2][128][32], Bs[2][96][32];
    const int t = threadIdx.x;
    const int lane = t & 63, w = t >> 6;
    const int bm = blockIdx.y * 128, bn = blockIdx.x * 96;
    const int wy = w >> 1, wx = w & 1;
    const int l15 = lane & 15, l4 = lane >> 4;

    int car[2], cas[2];
#pragma unroll
    for (int i = 0; i < 2; i++) {
        const int c = t + i * 256;
        car[i] = c >> 2;
        cas[i] = (((c & 3) ^ ((car[i] >> 1) & 3)) * 8);
    }
    const int cb0 = t, rb0 = cb0 >> 2, sb0 = (((cb0 & 3) ^ ((rb0 >> 1) & 3)) * 8);
    const int cb1 = t + 256, rb1 = cb1 >> 2, sb1 = (((cb1 & 3) ^ ((rb1 >> 1) & 3)) * 8);
    const bool bex = (t < 128);

    f32x4 acc[4][3] = {};

#define STG_P(k0_, buf)                                                                \
    {                                                                                  \
        _Float16* ab = &As[(buf)][0][0];                                               \
        _Float16* bb = &Bs[(buf)][0][0];                                               \
        _Pragma("unroll") for (int i = 0; i < 2; i++)                                  \
            glds16(A + (size_t)(bm + car[i]) * K + (k0_) + cas[i], ab + (t + i * 256) * 8); \
        glds16(B + (size_t)(bn + rb0) * K + (k0_) + sb0, bb + cb0 * 8);                \
        if (bex) glds16(B + (size_t)(bn + rb1) * K + (k0_) + sb1, bb + cb1 * 8);       \
    }

    STG_P(0, 0)

    int cur = 0;
    for (int k0 = 0; k0 < K; k0 += 32) {
        __syncthreads();
        if (k0 + 32 < K) STG_P(k0 + 32, cur ^ 1)
        h8 af[4], bf[3];
#pragma unroll
        for (int m = 0; m < 4; m++) {
            const int row = wy * 64 + m * 16 + l15;
            af[m] = ld8h(&As[cur][row][(l4 ^ ((row >> 1) & 3)) * 8]);
        }
#pragma unroll
        for (int n = 0; n < 3; n++) {
            const int row = wx * 48 + n * 16 + l15;
            bf[n] = ld8h(&Bs[cur][row][(l4 ^ ((row >> 1) & 3)) * 8]);
        }
#pragma unroll
        for (int m = 0; m < 4; m++)
#pragma unroll
            for (int n = 0; n < 3; n++)
                acc[m][n] = __builtin_amdgcn_mfma_f32_16x16x32_f16(af[m], bf[n], acc[m][n], 0, 0, 0);
        cur ^= 1;
    }
#undef STG_P

#pragma unroll
    for (int m = 0; m < 4; m++)
#pragma unroll
        for (int n = 0; n < 3; n++)
#pragma unroll
            for (int r = 0; r < 4; r++)
                C[(size_t)(bm + wy * 64 + m * 16 + l4 * 4 + r) * N + bn + wx * 48 + n * 16 + l15] =
                    acc[m][n][r];
}

// ---------------------------------------------------------------------------
// Flash attention, fp16 MFMA, diagonal-paired (uniform 17 tiles/phase-pair).
// 512 thr = 8 waves x 16 q-rows, KV tiles 64. K staged in LDS (dbuf + async
// reg prefetch). V NOT staged: per-head V (384 KB) is L2-resident and the
// V-frag access is a coalesced 16B/lane global load (Common-mistake #7:
// don't LDS-stage L2-fitting data). DS ops/wave-tile: 44 -> 30.
// Softmax: exp2 domain, screened max-reduce, deferred l-sum.
// ---------------------------------------------------------------------------
__global__ __launch_bounds__(512, 2) void attn_mfma(
    const _Float16* __restrict__ Qh, const _Float16* __restrict__ Kh,
    const _Float16* __restrict__ Vt, _Float16* __restrict__ Oh) {
    __shared__ _Float16 Ks[2][64][104];
    __shared__ _Float16 Ps[8][16][72];

    const float T2 = 11.5416f;  // 8 * log2(e): P bounded by e^8

    const int h = blockIdx.y;
    const int t = threadIdx.x, lane = t & 63, w = t >> 6;
    const int l15 = lane & 15, l4 = lane >> 4;

    const _Float16* Kg = Kh + (size_t)h * 2048 * 96;
    const _Float16* Vg = Vt + (size_t)h * 96 * 2048;

    // K staging: 64x96 tile = 768 us8-chunks; cA = t (all), cB = 512+t (t<256)
    const int cA = t, rKA = cA / 12, sKA = (cA % 12) * 8;
    const int cB = 512 + t, rKB = cB / 12, sKB = (cB % 12) * 8;
    const bool two = (t < 256);

    for (int ph = 0; ph < 2; ph++) {
        const int qt = ph ? (int)blockIdx.x : 15 - (int)blockIdx.x;
        const int q0 = qt * 128;
        const int wq = q0 + w * 16;

        h8 qf[3];
        const size_t qrow = ((size_t)h * 2048 + wq + l15) * 96;
#pragma unroll
        for (int kc = 0; kc < 3; kc++) qf[kc] = ld8h(Qh + qrow + kc * 32 + l4 * 8);

        us8 kregA, kregB;
        kregA = *(const us8*)(Kg + (size_t)rKA * 96 + sKA);
        if (two) kregB = *(const us8*)(Kg + (size_t)rKB * 96 + sKB);

        f32x4 o[6] = {};
        float m_i[4] = {-1e30f, -1e30f, -1e30f, -1e30f};
        float l_i[4] = {0.f, 0.f, 0.f, 0.f};

        const int nkt = 2 * qt + 2;
        for (int kt = 0; kt < nkt; kt++) {
            const int kv0 = kt * 64;
            const int buf = kt & 1;
            *(us8*)&Ks[buf][rKA][sKA] = kregA;
            if (two) *(us8*)&Ks[buf][rKB][sKB] = kregB;
            __syncthreads();
            if (kt + 1 < nkt) {  // prefetch next K tile into regs (T14)
                const int kv1 = kv0 + 64;
                kregA = *(const us8*)(Kg + (size_t)(kv1 + rKA) * 96 + sKA);
                if (two) kregB = *(const us8*)(Kg + (size_t)(kv1 + rKB) * 96 + sKB);
            }

            if (kv0 <= wq + 15) {  // tile visible to this wave
                // V frags direct from global (L2): issue early, independent
                h8 vb[2][6];
#pragma unroll
                for (int kc2 = 0; kc2 < 2; kc2++)
#pragma unroll
                    for (int f2 = 0; f2 < 6; f2++)
                        vb[kc2][f2] = ld8h(Vg + (size_t)(f2 * 16 + l15) * 2048 + kv0 + kc2 * 32 + l4 * 8);

                f32x4 s[4] = {};
#pragma unroll
                for (int f = 0; f < 4; f++)
#pragma unroll
                    for (int kc = 0; kc < 3; kc++) {
                        h8 kf = ld8h(&Ks[buf][f * 16 + l15][kc * 32 + l4 * 8]);
                        s[f] = __builtin_amdgcn_mfma_f32_16x16x32_f16(qf[kc], kf, s[f], 0, 0, 0);
                    }

                if (kv0 + 63 > wq) {  // diagonal-crossing: causal mask
#pragma unroll
                    for (int f = 0; f < 4; f++)
#pragma unroll
                        for (int r = 0; r < 4; r++)
                            if (kv0 + f * 16 + l15 > wq + l4 * 4 + r) s[f][r] = -1e30f;
                }

                // screened max: per-lane local max first (no shfl in common path)
                float lm[4];
                bool need = false;
#pragma unroll
                for (int r = 0; r < 4; r++) {
                    lm[r] = fmaxf(fmaxf(s[0][r], s[1][r]), fmaxf(s[2][r], s[3][r]));
                    need = need || (lm[r] > m_i[r] + T2);
                }
                if (__any(need)) {  // full row-max reduce + rescale (rare)
#pragma unroll
                    for (int r = 0; r < 4; r++) {
                        float m0 = lm[r];
#pragma unroll
                        for (int msk = 1; msk < 16; msk <<= 1) m0 = fmaxf(m0, __shfl_xor(m0, msk, 64));
                        const float mnew = fmaxf(m_i[r], m0);
                        const float sc = exp2f(m_i[r] - mnew);
                        m_i[r] = mnew;
                        l_i[r] *= sc;
#pragma unroll
                        for (int f2 = 0; f2 < 6; f2++) o[f2][r] *= sc;
                    }
                }

#pragma unroll
                for (int f = 0; f < 4; f++)
#pragma unroll
                    for (int r = 0; r < 4; r++) {
                        const float p = exp2f(s[f][r] - m_i[r]);
                        Ps[w][l4 * 4 + r][f * 16 + l15] = (_Float16)p;
                        l_i[r] += p;  // per-lane partial; reduced in epilogue
                    }
#pragma unroll
                for (int kc2 = 0; kc2 < 2; kc2++) {
                    h8 pa = ld8h(&Ps[w][l15][kc2 * 32 + l4 * 8]);
#pragma unroll
                    for (int f2 = 0; f2 < 6; f2++)
                        o[f2] = __builtin_amdgcn_mfma_f32_16x16x32_f16(pa, vb[kc2][f2], o[f2], 0, 0, 0);
                }
            }
        }

        __syncthreads();  // all waves done with LDS before next phase restages

#pragma unroll
        for (int r = 0; r < 4; r++) {
            float ss = l_i[r];
#pragma unroll
            for (int msk = 1; msk < 16; msk <<= 1) ss += __shfl_xor(ss, msk, 64);
            const float inv = 1.0f / ss;
            const size_t row = (size_t)(wq + l4 * 4 + r) * 3072 + h * 96;
#pragma unroll
            for (int f2 = 0; f2 < 6; f2++)
                Oh[row + f2 * 16 + l15] = (_Float16)(o[f2][r] * inv);
        }
    }
}

// ---------------------------------------------------------------------------
extern "C" void kernel_launch(void* const* d_in, const int* in_sizes, int n_in,
                              void* d_out, int out_size, void* d_ws, size_t ws_size,
                              hipStream_t stream) {
    const float* x = (const float*)d_in[0];
    const float* w_qkv = (const float*)d_in[1];
    const float* w_o = (const float*)d_in[2];
    const float* sf = (const float*)d_in[3];
    float* out = (float*)d_out;
    char* ws = (char*)d_ws;

    _Float16* wqkvh = (_Float16*)(ws);             // [0, 56.6MB)
    _Float16* Qh = (_Float16*)(ws + 56623104);
    _Float16* Kh = (_Float16*)(ws + 69206016);
    _Float16* Vth = (_Float16*)(ws + 81788928);
    _Float16* Oh = (_Float16*)(ws + 94371840);
    _Float16* xh = (_Float16*)(ws + 132120576);
    _Float16* woh = (_Float16*)(ws + 144703488);
    float* cs = (float*)(ws + 163577856);
    float* sn = (float*)(ws + 163971072);

    const float rope_scale = (float)sqrt(1.0 + log(131072.0 / 4096.0) / log(4096.0));
    // attn_scale * log2(e): attention computes exp2 directly
    const float q_scale = (float)((1.0 / sqrt(96.0)) * 1.4426950408889634);

    convert_half<<<3072, 256, 0, stream>>>(x, xh, 786432);
    convert_half<<<13824, 256, 0, stream>>>(w_qkv, wqkvh, 3538944);
    rope_table<<<384, 256, 0, stream>>>(sf, cs, sn, rope_scale);
    gemm_qkv<<<dim3(48, 16), 256, 0, stream>>>(xh, wqkvh, cs, sn, Qh, Kh, Vth, q_scale);
    convert_half<<<4608, 256, 0, stream>>>(w_o, woh, 1179648);
    attn_mfma<<<dim3(8, 32), 512, 0, stream>>>(Qh, Kh, Vth, Oh);
    gemm_p<<<dim3(32, 16), 256, 0, stream>>>(Oh, woh, out, 2048, 3072, 3072);
}

// Round 17
// 316.224 us; speedup vs baseline: 1.0925x; 1.0925x over previous
//
#include <hip/hip_runtime.h>
#include <math.h>

typedef __attribute__((ext_vector_type(4))) float f32x4;
typedef __attribute__((ext_vector_type(4))) float f4;
typedef __attribute__((ext_vector_type(8))) _Float16 h8;
typedef __attribute__((ext_vector_type(4))) _Float16 h4;
typedef __attribute__((ext_vector_type(8))) unsigned short us8;

static __device__ __forceinline__ h8 ld8h(const _Float16* p) {
    return __builtin_bit_cast(h8, *(const us8*)p);
}
static __device__ __forceinline__ void glds16(const void* g, void* l) {
    __builtin_amdgcn_global_load_lds((const __attribute__((address_space(1))) unsigned int*)g,
                                     (__attribute__((address_space(3))) unsigned int*)l, 16, 0, 0);
}
static __device__ __forceinline__ void cvt8(const float* __restrict__ in,
                                            _Float16* __restrict__ out, int i) {
    f4 v0 = *(const f4*)(in + (size_t)i * 8);
    f4 v1 = *(const f4*)(in + (size_t)i * 8 + 4);
    h8 o;
#pragma unroll
    for (int j = 0; j < 4; j++) {
        o[j] = (_Float16)v0[j];
        o[j + 4] = (_Float16)v1[j];
    }
    *(h8*)(out + (size_t)i * 8) = o;
}

// ---------------------------------------------------------------------------
// Fused prep: x->fp16 (3072 blks), w_qkv->fp16 (13824), w_o->fp16 (4608),
// SuRoPE cos/sin table (384). All independent, memory-bound; one launch.
// ---------------------------------------------------------------------------
__global__ void prep(const float* __restrict__ x, const float* __restrict__ wqkv,
                     const float* __restrict__ wo, const float* __restrict__ sf,
                     _Float16* __restrict__ xh, _Float16* __restrict__ wqkvh,
                     _Float16* __restrict__ woh, float* __restrict__ cs,
                     float* __restrict__ sn, float rope_scale) {
    const int b = blockIdx.x, t = threadIdx.x;
    if (b < 3072) {
        cvt8(x, xh, b * 256 + t);
    } else if (b < 16896) {
        cvt8(wqkv, wqkvh, (b - 3072) * 256 + t);
    } else if (b < 21504) {
        cvt8(wo, woh, (b - 16896) * 256 + t);
    } else {
        const int i = (b - 21504) * 256 + t;  // 2048*48
        const int j = i % 48, l = i / 48;
        const float e = (float)(2 * j) / 96.0f;
        const float inv = 1.0f / (sf[j] * powf(10000.0f, e));
        const float ang = (float)l * inv;
        cs[i] = cosf(ang) * rope_scale;
        sn[i] = sinf(ang) * rope_scale;
    }
}

// ---------------------------------------------------------------------------
// QKV GEMM, fused SuRoPE + head-split + V-transpose epilogue. BM=128, BN=192,
// grid 48x16 = 768 blocks = exactly 3/CU. Q scaled by attn_scale*log2(e).
// ---------------------------------------------------------------------------
__global__ __launch_bounds__(256, 3) void gemm_qkv(
    const _Float16* __restrict__ A, const _Float16* __restrict__ B,
    const float* __restrict__ cs, const float* __restrict__ sn,
    _Float16* __restrict__ Qh, _Float16* __restrict__ Kh, _Float16* __restrict__ Vt,
    float q_scale) {
    const int K = 3072;
    __shared__ _Float16 As[2][128][32], Bs[2][192][32];
    const int t = threadIdx.x;
    const int lane = t & 63, w = t >> 6;
    const int bm = blockIdx.y * 128, bn = blockIdx.x * 192;
    const int wm = w >> 1, wn = w & 1;
    const int l15 = lane & 15, l4 = lane >> 4;

    int car[2], cas[2], cbr[3], cbs[3];
#pragma unroll
    for (int i = 0; i < 2; i++) {
        const int c = t + i * 256;
        car[i] = c >> 2;
        cas[i] = (((c & 3) ^ ((car[i] >> 1) & 3)) * 8);
    }
#pragma unroll
    for (int i = 0; i < 3; i++) {
        const int c = t + i * 256;
        cbr[i] = c >> 2;
        cbs[i] = (((c & 3) ^ ((cbr[i] >> 1) & 3)) * 8);
    }

    f32x4 acc[4][6] = {};

#define STG_QKV(k0_, buf)                                                              \
    {                                                                                  \
        _Float16* ab = &As[(buf)][0][0];                                               \
        _Float16* bb = &Bs[(buf)][0][0];                                               \
        _Pragma("unroll") for (int i = 0; i < 2; i++)                                  \
            glds16(A + (size_t)(bm + car[i]) * K + (k0_) + cas[i], ab + (t + i * 256) * 8); \
        _Pragma("unroll") for (int i = 0; i < 3; i++)                                  \
            glds16(B + (size_t)(bn + cbr[i]) * K + (k0_) + cbs[i], bb + (t + i * 256) * 8); \
    }

    STG_QKV(0, 0)

    int cur = 0;
    for (int k0 = 0; k0 < K; k0 += 32) {
        __syncthreads();
        if (k0 + 32 < K) STG_QKV(k0 + 32, cur ^ 1)
        h8 af[4], bf[6];
#pragma unroll
        for (int m = 0; m < 4; m++) {
            const int row = wm * 64 + m * 16 + l15;
            af[m] = ld8h(&As[cur][row][(l4 ^ ((row >> 1) & 3)) * 8]);
        }
#pragma unroll
        for (int n = 0; n < 6; n++) {
            const int row = wn * 96 + n * 16 + l15;
            bf[n] = ld8h(&Bs[cur][row][(l4 ^ ((row >> 1) & 3)) * 8]);
        }
#pragma unroll
        for (int m = 0; m < 4; m++)
#pragma unroll
            for (int n = 0; n < 6; n++)
                acc[m][n] = __builtin_amdgcn_mfma_f32_16x16x32_f16(af[m], bf[n], acc[m][n], 0, 0, 0);
        cur ^= 1;
    }
#undef STG_QKV

    const int opcol0 = bn + wn * 96;
    const int which = opcol0 / 3072;
    const int h = (opcol0 % 3072) / 96;

    if (which == 2) {
        // fused transpose: Vt[h][d][l], d = n*16+l15, l = bm+wm*64+m*16+l4*4+r
#pragma unroll
        for (int m = 0; m < 4; m++)
#pragma unroll
            for (int n = 0; n < 6; n++) {
                h4 v;
#pragma unroll
                for (int r = 0; r < 4; r++) v[r] = (_Float16)acc[m][n][r];
                *(h4*)(Vt + ((size_t)h * 96 + n * 16 + l15) * 2048 + bm + wm * 64 + m * 16 + l4 * 4) = v;
            }
    } else {
        _Float16* dst = (which == 0) ? Qh : Kh;
        const float qs = (which == 0) ? q_scale : 1.0f;
#pragma unroll
        for (int m = 0; m < 4; m++)
#pragma unroll
            for (int r = 0; r < 4; r++) {
                const int l = bm + wm * 64 + m * 16 + l4 * 4 + r;
                const float* csl = cs + l * 48;
                const float* snl = sn + l * 48;
                const size_t rowb = ((size_t)h * 2048 + l) * 96;
#pragma unroll
                for (int n = 0; n < 3; n++) {
                    const int j = n * 16 + l15;
                    const float c = csl[j], s = snl[j];
                    const float lo = acc[m][n][r], hi = acc[m][n + 3][r];
                    dst[rowb + j] = (_Float16)((lo * c - hi * s) * qs);
                    dst[rowb + j + 48] = (_Float16)((hi * c + lo * s) * qs);
                }
            }
    }
}

// ---------------------------------------------------------------------------
// Projection GEMM: BM=128, BN=96, grid 32x16 = 512 blocks = uniform 2/CU.
// ---------------------------------------------------------------------------
__global__ __launch_bounds__(256, 3) void gemm_p(
    const _Float16* __restrict__ A, const _Float16* __restrict__ B,
    float* __restrict__ C, int M, int N, int K) {
    __shared__ _Float16 As[2][128][32], Bs[2][96][32];
    const int t = threadIdx.x;
    const int lane = t & 63, w = t >> 6;
    const int bm = blockIdx.y * 128, bn = blockIdx.x * 96;
    const int wy = w >> 1, wx = w & 1;
    const int l15 = lane & 15, l4 = lane >> 4;

    int car[2], cas[2];
#pragma unroll
    for (int i = 0; i < 2; i++) {
        const int c = t + i * 256;
        car[i] = c >> 2;
        cas[i] = (((c & 3) ^ ((car[i] >> 1) & 3)) * 8);
    }
    const int cb0 = t, rb0 = cb0 >> 2, sb0 = (((cb0 & 3) ^ ((rb0 >> 1) & 3)) * 8);
    const int cb1 = t + 256, rb1 = cb1 >> 2, sb1 = (((cb1 & 3) ^ ((rb1 >> 1) & 3)) * 8);
    const bool bex = (t < 128);

    f32x4 acc[4][3] = {};

#define STG_P(k0_, buf)                                                                \
    {                                                                                  \
        _Float16* ab = &As[(buf)][0][0];                                               \
        _Float16* bb = &Bs[(buf)][0][0];                                               \
        _Pragma("unroll") for (int i = 0; i < 2; i++)                                  \
            glds16(A + (size_t)(bm + car[i]) * K + (k0_) + cas[i], ab + (t + i * 256) * 8); \
        glds16(B + (size_t)(bn + rb0) * K + (k0_) + sb0, bb + cb0 * 8);                \
        if (bex) glds16(B + (size_t)(bn + rb1) * K + (k0_) + sb1, bb + cb1 * 8);       \
    }

    STG_P(0, 0)

    int cur = 0;
    for (int k0 = 0; k0 < K; k0 += 32) {
        __syncthreads();
        if (k0 + 32 < K) STG_P(k0 + 32, cur ^ 1)
        h8 af[4], bf[3];
#pragma unroll
        for (int m = 0; m < 4; m++) {
            const int row = wy * 64 + m * 16 + l15;
            af[m] = ld8h(&As[cur][row][(l4 ^ ((row >> 1) & 3)) * 8]);
        }
#pragma unroll
        for (int n = 0; n < 3; n++) {
            const int row = wx * 48 + n * 16 + l15;
            bf[n] = ld8h(&Bs[cur][row][(l4 ^ ((row >> 1) & 3)) * 8]);
        }
#pragma unroll
        for (int m = 0; m < 4; m++)
#pragma unroll
            for (int n = 0; n < 3; n++)
                acc[m][n] = __builtin_amdgcn_mfma_f32_16x16x32_f16(af[m], bf[n], acc[m][n], 0, 0, 0);
        cur ^= 1;
    }
#undef STG_P

#pragma unroll
    for (int m = 0; m < 4; m++)
#pragma unroll
        for (int n = 0; n < 3; n++)
#pragma unroll
            for (int r = 0; r < 4; r++)
                C[(size_t)(bm + wy * 64 + m * 16 + l4 * 4 + r) * N + bn + wx * 48 + n * 16 + l15] =
                    acc[m][n][r];
}

// ---------------------------------------------------------------------------
// Flash attention, fp16 MFMA, diagonal-paired (uniform 17 tiles/phase-pair).
// R15 structure (best known): 512 thr = 8 waves x 16 q-rows, KV tiles 64,
// K AND V staged in LDS (dbuf + async reg prefetch — staging is also the
// latency-scheduling device; R16 showed L2-direct V costs +36 µs).
// Softmax: exp2 domain, screened max-reduce, deferred l-sum.
// ---------------------------------------------------------------------------
__global__ __launch_bounds__(512, 2) void attn_mfma(
    const _Float16* __restrict__ Qh, const _Float16* __restrict__ Kh,
    const _Float16* __restrict__ Vt, _Float16* __restrict__ Oh) {
    __shared__ _Float16 Ks[2][64][104];
    __shared__ _Float16 Vs[2][96][72];
    __shared__ _Float16 Ps[8][16][72];

    const float T2 = 11.5416f;  // 8 * log2(e): P bounded by e^8

    const int h = blockIdx.y;
    const int t = threadIdx.x, lane = t & 63, w = t >> 6;
    const int l15 = lane & 15, l4 = lane >> 4;

    const _Float16* Kg = Kh + (size_t)h * 2048 * 96;
    const _Float16* Vg = Vt + (size_t)h * 96 * 2048;

    const int cA = t, rKA = cA / 12, sKA = (cA % 12) * 8;
    const int rVA = cA >> 3, sVA = (cA & 7) * 8;
    const int cB = 512 + t, rKB = cB / 12, sKB = (cB % 12) * 8;
    const int rVB = cB >> 3, sVB = (cB & 7) * 8;
    const bool two = (t < 256);

    for (int ph = 0; ph < 2; ph++) {
        const int qt = ph ? (int)blockIdx.x : 15 - (int)blockIdx.x;
        const int q0 = qt * 128;
        const int wq = q0 + w * 16;

        h8 qf[3];
        const size_t qrow = ((size_t)h * 2048 + wq + l15) * 96;
#pragma unroll
        for (int kc = 0; kc < 3; kc++) qf[kc] = ld8h(Qh + qrow + kc * 32 + l4 * 8);

        us8 kregA, vregA, kregB, vregB;
        kregA = *(const us8*)(Kg + (size_t)rKA * 96 + sKA);
        vregA = *(const us8*)(Vg + (size_t)rVA * 2048 + sVA);
        if (two) {
            kregB = *(const us8*)(Kg + (size_t)rKB * 96 + sKB);
            vregB = *(const us8*)(Vg + (size_t)rVB * 2048 + sVB);
        }

        f32x4 o[6] = {};
        float m_i[4] = {-1e30f, -1e30f, -1e30f, -1e30f};
        float l_i[4] = {0.f, 0.f, 0.f, 0.f};

        const int nkt = 2 * qt + 2;
        for (int kt = 0; kt < nkt; kt++) {
            const int kv0 = kt * 64;
            const int buf = kt & 1;
            *(us8*)&Ks[buf][rKA][sKA] = kregA;
            *(us8*)&Vs[buf][rVA][sVA] = vregA;
            if (two) {
                *(us8*)&Ks[buf][rKB][sKB] = kregB;
                *(us8*)&Vs[buf][rVB][sVB] = vregB;
            }
            __syncthreads();
            if (kt + 1 < nkt) {  // prefetch next tile into regs (T14)
                const int kv1 = kv0 + 64;
                kregA = *(const us8*)(Kg + (size_t)(kv1 + rKA) * 96 + sKA);
                vregA = *(const us8*)(Vg + (size_t)rVA * 2048 + kv1 + sVA);
                if (two) {
                    kregB = *(const us8*)(Kg + (size_t)(kv1 + rKB) * 96 + sKB);
                    vregB = *(const us8*)(Vg + (size_t)rVB * 2048 + kv1 + sVB);
                }
            }

            if (kv0 <= wq + 15) {  // tile visible to this wave
                f32x4 s[4] = {};
#pragma unroll
                for (int f = 0; f < 4; f++)
#pragma unroll
                    for (int kc = 0; kc < 3; kc++) {
                        h8 kf = ld8h(&Ks[buf][f * 16 + l15][kc * 32 + l4 * 8]);
                        s[f] = __builtin_amdgcn_mfma_f32_16x16x32_f16(qf[kc], kf, s[f], 0, 0, 0);
                    }

                if (kv0 + 63 > wq) {  // diagonal-crossing: causal mask
#pragma unroll
                    for (int f = 0; f < 4; f++)
#pragma unroll
                        for (int r = 0; r < 4; r++)
                            if (kv0 + f * 16 + l15 > wq + l4 * 4 + r) s[f][r] = -1e30f;
                }

                // screened max: per-lane local max first (no shfl in common path)
                float lm[4];
                bool need = false;
#pragma unroll
                for (int r = 0; r < 4; r++) {
                    lm[r] = fmaxf(fmaxf(s[0][r], s[1][r]), fmaxf(s[2][r], s[3][r]));
                    need = need || (lm[r] > m_i[r] + T2);
                }
                if (__any(need)) {  // full row-max reduce + rescale (rare)
#pragma unroll
                    for (int r = 0; r < 4; r++) {
                        float m0 = lm[r];
#pragma unroll
                        for (int msk = 1; msk < 16; msk <<= 1) m0 = fmaxf(m0, __shfl_xor(m0, msk, 64));
                        const float mnew = fmaxf(m_i[r], m0);
                        const float sc = exp2f(m_i[r] - mnew);
                        m_i[r] = mnew;
                        l_i[r] *= sc;
#pragma unroll
                        for (int f2 = 0; f2 < 6; f2++) o[f2][r] *= sc;
                    }
                }

#pragma unroll
                for (int f = 0; f < 4; f++)
#pragma unroll
                    for (int r = 0; r < 4; r++) {
                        const float p = exp2f(s[f][r] - m_i[r]);
                        Ps[w][l4 * 4 + r][f * 16 + l15] = (_Float16)p;
                        l_i[r] += p;  // per-lane partial; reduced in epilogue
                    }
#pragma unroll
                for (int kc2 = 0; kc2 < 2; kc2++) {
                    h8 pa = ld8h(&Ps[w][l15][kc2 * 32 + l4 * 8]);
#pragma unroll
                    for (int f2 = 0; f2 < 6; f2++) {
                        h8 vb = ld8h(&Vs[buf][f2 * 16 + l15][kc2 * 32 + l4 * 8]);
                        o[f2] = __builtin_amdgcn_mfma_f32_16x16x32_f16(pa, vb, o[f2], 0, 0, 0);
                    }
                }
            }
        }

        __syncthreads();  // all waves done with LDS before next phase restages

#pragma unroll
        for (int r = 0; r < 4; r++) {
            float ss = l_i[r];
#pragma unroll
            for (int msk = 1; msk < 16; msk <<= 1) ss += __shfl_xor(ss, msk, 64);
            const float inv = 1.0f / ss;
            const size_t row = (size_t)(wq + l4 * 4 + r) * 3072 + h * 96;
#pragma unroll
            for (int f2 = 0; f2 < 6; f2++)
                Oh[row + f2 * 16 + l15] = (_Float16)(o[f2][r] * inv);
        }
    }
}

// ---------------------------------------------------------------------------
extern "C" void kernel_launch(void* const* d_in, const int* in_sizes, int n_in,
                              void* d_out, int out_size, void* d_ws, size_t ws_size,
                              hipStream_t stream) {
    const float* x = (const float*)d_in[0];
    const float* w_qkv = (const float*)d_in[1];
    const float* w_o = (const float*)d_in[2];
    const float* sf = (const float*)d_in[3];
    float* out = (float*)d_out;
    char* ws = (char*)d_ws;

    _Float16* wqkvh = (_Float16*)(ws);             // [0, 56.6MB)
    _Float16* Qh = (_Float16*)(ws + 56623104);
    _Float16* Kh = (_Float16*)(ws + 69206016);
    _Float16* Vth = (_Float16*)(ws + 81788928);
    _Float16* Oh = (_Float16*)(ws + 94371840);
    _Float16* xh = (_Float16*)(ws + 132120576);
    _Float16* woh = (_Float16*)(ws + 144703488);
    float* cs = (float*)(ws + 163577856);
    float* sn = (float*)(ws + 163971072);

    const float rope_scale = (float)sqrt(1.0 + log(131072.0 / 4096.0) / log(4096.0));
    // attn_scale * log2(e): attention computes exp2 directly
    const float q_scale = (float)((1.0 / sqrt(96.0)) * 1.4426950408889634);

    prep<<<21888, 256, 0, stream>>>(x, w_qkv, w_o, sf, xh, wqkvh, woh, cs, sn, rope_scale);
    gemm_qkv<<<dim3(48, 16), 256, 0, stream>>>(xh, wqkvh, cs, sn, Qh, Kh, Vth, q_scale);
    attn_mfma<<<dim3(8, 32), 512, 0, stream>>>(Qh, Kh, Vth, Oh);
    gemm_p<<<dim3(32, 16), 256, 0, stream>>>(Oh, woh, out, 2048, 3072, 3072);
}